// Round 4
// baseline (663.298 us; speedup 1.0000x reference)
//
#include <hip/hip_runtime.h>
#include <cstdint>

// LSTM cell: B=4096, N_IN=2048, N_OUT=2048.
// gates = [x|h_old](4096x4096) @ Wp^T + b ; Wp rows gate-interleaved: Wp[4j+q]=W_q[j].
// R4: (a) pack kernel rewritten unit-stride (float4 in, uint2 out, 4 elems/thread);
//     (b) GEMM switched to mfma_f32_32x32x16_bf16 (half the MFMA insts, faster pipe),
//         XOR LDS swizzle kept, bias in epilogue (R2 showed acc-fold costs occupancy).
// ws layout: t bf16 (32MB) @0, Wp bf16 (64MB) @32MB. Requires ws_size >= 96MB.

#define B_DIM 4096
#define NIN   2048
#define NOUT  2048
#define K_DIM 4096   // NIN + NOUT
#define NG    8192   // 4 * NOUT

#define BM 128
#define BN 128
#define BK 32

typedef __attribute__((ext_vector_type(8))) short bf16x8;    // 8 bf16 = 4 VGPRs
typedef __attribute__((ext_vector_type(16))) float f32x16;   // 32x32 accumulator

__device__ inline unsigned short f2bf(float f) {
    uint32_t u = __float_as_uint(f);
    uint32_t r = (u + 0x7fffu + ((u >> 16) & 1u)) >> 16;     // round-to-nearest-even
    return (unsigned short)r;
}

__device__ inline float sel4(float a, float b, float c, float d, int s) {
    float x = (s & 1) ? b : a;
    float y = (s & 1) ? d : c;
    return (s & 2) ? y : x;
}

// ---- pack kernel v2: one thread = 4 contiguous f32 -> 4 bf16 ----
// lane reads float4 at 16B stride (1 KB/wave/inst, unit-stride) and stores
// uint2 at 8B stride (512 B/wave/inst, unit-stride). No strided gaps.
#define TBLK2 ((B_DIM * K_DIM / 4) / 256)   // 16384 blocks for t
#define WBLK2 ((NG * K_DIM / 4) / 256)      // 32768 blocks for Wp
__global__ void pack_kernel(const float* __restrict__ x,
                            const float* __restrict__ h_old,
                            const float* __restrict__ Wf, const float* __restrict__ Wi,
                            const float* __restrict__ Wo, const float* __restrict__ Wg,
                            unsigned short* __restrict__ t,
                            unsigned short* __restrict__ Wp) {
    const float* src;
    unsigned short* dst;
    int e;                                   // index in float4 units
    if (blockIdx.x < TBLK2) {
        e = blockIdx.x * 256 + threadIdx.x;
        int b = e >> 10;                     // 1024 float4-chunks per row of K=4096
        int k = (e & 1023) << 2;
        src = (k < NIN) ? (x + (size_t)b * NIN + k)
                        : (h_old + (size_t)b * NOUT + (k - NIN));
        dst = t;
    } else {
        e = (blockIdx.x - TBLK2) * 256 + threadIdx.x;
        int row = e >> 10;
        int k = (e & 1023) << 2;
        int jf = row >> 2, q = row & 3;
        src = ((q == 0) ? Wf : (q == 1) ? Wi : (q == 2) ? Wo : Wg)
              + (size_t)jf * K_DIM + k;
        dst = Wp;
    }
    float4 v = *(const float4*)src;
    uint2 o;
    o.x = f2bf(v.x) | ((uint32_t)f2bf(v.y) << 16);
    o.y = f2bf(v.z) | ((uint32_t)f2bf(v.w) << 16);
    ((uint2*)dst)[e] = o;
}

#define GL2LDS(g, l) \
    __builtin_amdgcn_global_load_lds((const __attribute__((address_space(1))) void*)(g), \
                                     (__attribute__((address_space(3))) void*)(l), 16, 0, 0)

// ---- fused GEMM (32x32x16 MFMA) + LSTM epilogue ----
__global__ __launch_bounds__(256)
void lstm_gemm_kernel(const unsigned short* __restrict__ T,   // (B, K) bf16
                      const unsigned short* __restrict__ Wp,  // (NG, K) bf16
                      const float* __restrict__ bf_, const float* __restrict__ bi_,
                      const float* __restrict__ bo_, const float* __restrict__ bg_,
                      const float* __restrict__ c_old,
                      float* __restrict__ c_out, float* __restrict__ h_out) {
    __shared__ __align__(16) unsigned short As[BM * BK];  // 8 KB, row stride 64 B
    __shared__ __align__(16) unsigned short Bs[BN * BK];  // 8 KB

    const int tid  = threadIdx.x;
    const int lane = tid & 63;
    const int w    = tid >> 6;
    const int m0   = blockIdx.y * BM;
    const int n0   = blockIdx.x * BN;
    const int wrow = (w >> 1) * 64;
    const int wcol = (w & 1) * 64;

    // staging: lane writes LDS at tid*16B (row=tid>>2, stored chunk pos=tid&3).
    // XOR swizzle: stored pos p holds logical chunk p ^ ((row>>1)&3) ->
    // global source chunk for this lane = (tid&3) ^ ((tid>>3)&3).
    const int arow = tid >> 2;
    const int koff = (((tid & 3) ^ ((tid >> 3) & 3)) << 3);
    const unsigned short* Ag = T  + (size_t)(m0 + arow) * K_DIM + koff;
    const unsigned short* Bg = Wp + (size_t)(n0 + arow) * K_DIM + koff;

    f32x16 acc[2][2];
#pragma unroll
    for (int i = 0; i < 2; ++i)
#pragma unroll
        for (int j = 0; j < 2; ++j)
            acc[i][j] = (f32x16){0,0,0,0,0,0,0,0,0,0,0,0,0,0,0,0};

    // 32x32x16 A/B fragment: m(or n) = lane&31, k = 8*(lane>>5) + elem.
    const int rsel = lane & 31;
    const int half = lane >> 5;
    const int kg   = (rsel >> 1) & 3;       // row-dependent swizzle term

    for (int kt = 0; kt < K_DIM; kt += BK) {
        GL2LDS(Ag + kt,                      As + tid * 8);
        GL2LDS(Ag + (size_t)64 * K_DIM + kt, As + 2048 + tid * 8);
        GL2LDS(Bg + kt,                      Bs + tid * 8);
        GL2LDS(Bg + (size_t)64 * K_DIM + kt, Bs + 2048 + tid * 8);
        __syncthreads();

        const bf16x8* Asv = (const bf16x8*)As;
        const bf16x8* Bsv = (const bf16x8*)Bs;
        bf16x8 af[2][2], bfr[2][2];         // [tile][kstep]
#pragma unroll
        for (int i = 0; i < 2; ++i)
#pragma unroll
            for (int s = 0; s < 2; ++s)
                af[i][s] = Asv[(wrow + 32 * i + rsel) * 4 + ((2 * s + half) ^ kg)];
#pragma unroll
        for (int j = 0; j < 2; ++j)
#pragma unroll
            for (int s = 0; s < 2; ++s)
                bfr[j][s] = Bsv[(wcol + 32 * j + rsel) * 4 + ((2 * s + half) ^ kg)];
#pragma unroll
        for (int s = 0; s < 2; ++s)
#pragma unroll
            for (int i = 0; i < 2; ++i)
#pragma unroll
                for (int j = 0; j < 2; ++j)
                    acc[i][j] = __builtin_amdgcn_mfma_f32_32x32x16_bf16(
                        af[i][s], bfr[j][s], acc[i][j], 0, 0, 0);
        __syncthreads();
    }

    // ---- epilogue ----
    // C/D map (32x32): col = lane&31, row = (reg&3) + 8*(reg>>2) + 4*(lane>>5).
    // col n = n0+wcol+32j+(lane&31): gate q = n&3 = lane&3, feature = n>>2.
    const int q = lane & 3;
    const float* bsrc = (q == 0) ? bf_ : (q == 1) ? bi_ : (q == 2) ? bo_ : bg_;
    float bias[2];
#pragma unroll
    for (int j = 0; j < 2; ++j)
        bias[j] = bsrc[(n0 + wcol + 32 * j + rsel) >> 2];

#pragma unroll
    for (int i = 0; i < 2; ++i) {
#pragma unroll
        for (int j = 0; j < 2; ++j) {
            const int featbase = ((n0 + wcol + 32 * j) >> 2) + (rsel >> 2);
#pragma unroll
            for (int g4 = 0; g4 < 4; ++g4) {
                const int rowq = m0 + wrow + 32 * i + 8 * g4 + 4 * half;
#pragma unroll
                for (int rr = 0; rr < 4; ++rr) {
                    float z = acc[i][j][4 * g4 + rr] + bias[j];
                    float v;
                    if (q == 3) {                       // tanh for gate g
                        v = 1.f - 2.f / (__expf(2.f * z) + 1.f);
                    } else {                            // sigmoid for f,i,o
                        v = 1.f / (1.f + __expf(-z));
                    }
                    float v1 = __shfl_xor(v, 1);
                    float v2 = __shfl_xor(v, 2);
                    float v3 = __shfl_xor(v, 3);
                    float fg = sel4(v, v1, v2, v3, q);
                    float ig = sel4(v, v1, v2, v3, q ^ 1);
                    float og = sel4(v, v1, v2, v3, q ^ 2);
                    float gg = sel4(v, v1, v2, v3, q ^ 3);
                    if ((lane & 3) == rr) {             // one lane per row of group
                        const size_t off = (size_t)(rowq + rr) * NOUT + featbase;
                        float co = c_old[off];
                        float c  = fg * co + ig * gg;
                        float h  = og * (1.f - 2.f / (__expf(2.f * c) + 1.f));
                        c_out[off] = c;
                        h_out[off] = h;
                    }
                }
            }
        }
    }
}

extern "C" void kernel_launch(void* const* d_in, const int* in_sizes, int n_in,
                              void* d_out, int out_size, void* d_ws, size_t ws_size,
                              hipStream_t stream) {
    const float* c_old = (const float*)d_in[0];
    const float* h_old = (const float*)d_in[1];
    const float* x     = (const float*)d_in[2];
    const float* Wf    = (const float*)d_in[3];
    const float* bf_   = (const float*)d_in[4];
    const float* Wi    = (const float*)d_in[5];
    const float* bi_   = (const float*)d_in[6];
    const float* Wo    = (const float*)d_in[7];
    const float* bo_   = (const float*)d_in[8];
    const float* Wg    = (const float*)d_in[9];
    const float* bg_   = (const float*)d_in[10];

    unsigned short* t  = (unsigned short*)d_ws;                           // 32 MB
    unsigned short* Wp = (unsigned short*)d_ws + (size_t)B_DIM * K_DIM;   // 64 MB

    float* c_out = (float*)d_out;
    float* h_out = (float*)d_out + (size_t)B_DIM * NOUT;

    pack_kernel<<<TBLK2 + WBLK2, 256, 0, stream>>>(x, h_old, Wf, Wi, Wo, Wg, t, Wp);

    dim3 grid(NG / BN, B_DIM / BM);   // 64 x 32
    lstm_gemm_kernel<<<grid, 256, 0, stream>>>(t, Wp, bf_, bi_, bo_, bg_,
                                               c_old, c_out, h_out);
}